// Round 4
// baseline (106.131 us; speedup 1.0000x reference)
//
#include <hip/hip_runtime.h>
#include <math.h>

#define NN 1024
#define IN_F 256
#define OUT_F 128
#define NHEADS 4
#define NHF 32

// K1: g_l = h @ Wl^T, g_r = h @ Wr^T -> [head][row][f] fp32.
// Grid (256 row-groups, 2 halves) = 512 blocks (2/CU, 8 waves/CU). Block 256 thr:
// tid -> (col 0..127 within half, k-half 0/1). W-row loads are per-thread
// (L2-hot, full line use over the k loop); h loads are wave-uniform -> s_load.
// Split-k combined through 4 KB LDS.
__global__ void __launch_bounds__(256) glr_gemm(const float* __restrict__ hmat,
                                                const float* __restrict__ Wl,
                                                const float* __restrict__ Wr,
                                                float* __restrict__ glh,
                                                float* __restrict__ grh) {
    const int tid  = threadIdx.x;
    const int r0   = blockIdx.x * 4;
    const int half = blockIdx.y;          // 0 -> Wl/glh, 1 -> Wr/grh
    const int cl   = tid & 127;           // col within half
    const int kh   = tid >> 7;            // k-half (wave-uniform: waves 0,1 -> 0; 2,3 -> 1)

    const float* __restrict__ W = half ? Wr : Wl;
    const float4* __restrict__ w4 = (const float4*)(W + cl * IN_F + kh * 128);
    const float4* __restrict__ h0 = (const float4*)(hmat + (r0 + 0) * IN_F + kh * 128);
    const float4* __restrict__ h1 = (const float4*)(hmat + (r0 + 1) * IN_F + kh * 128);
    const float4* __restrict__ h2 = (const float4*)(hmat + (r0 + 2) * IN_F + kh * 128);
    const float4* __restrict__ h3 = (const float4*)(hmat + (r0 + 3) * IN_F + kh * 128);

    float a0 = 0.f, a1 = 0.f, a2 = 0.f, a3 = 0.f;
#pragma unroll 8
    for (int q = 0; q < 32; ++q) {
        const float4 w  = w4[q];
        const float4 x0 = h0[q];   // wave-uniform address -> s_load
        const float4 x1 = h1[q];
        const float4 x2 = h2[q];
        const float4 x3 = h3[q];
        a0 = fmaf(w.x, x0.x, fmaf(w.y, x0.y, fmaf(w.z, x0.z, fmaf(w.w, x0.w, a0))));
        a1 = fmaf(w.x, x1.x, fmaf(w.y, x1.y, fmaf(w.z, x1.z, fmaf(w.w, x1.w, a1))));
        a2 = fmaf(w.x, x2.x, fmaf(w.y, x2.y, fmaf(w.z, x2.z, fmaf(w.w, x2.w, a2))));
        a3 = fmaf(w.x, x3.x, fmaf(w.y, x3.y, fmaf(w.z, x3.z, fmaf(w.w, x3.w, a3))));
    }

    __shared__ float cmb[2][4][128];
    cmb[kh][0][cl] = a0;
    cmb[kh][1][cl] = a1;
    cmb[kh][2][cl] = a2;
    cmb[kh][3][cl] = a3;
    __syncthreads();

    float* __restrict__ dst = half ? grh : glh;
#pragma unroll
    for (int t = 0; t < 2; ++t) {
        const int idx = tid + t * 256;        // 512 outputs, 2 per thread
        const int r = idx >> 7, c = idx & 127;
        const float v = cmb[0][r][c] + cmb[1][r][c];
        const int hh = c >> 5, f = c & 31;
        dst[(hh * NN + r0 + r) * NHF + f] = v;
    }
}

// K2: unchanged from round 2 (kept identical to isolate K1's delta).
__global__ void __launch_bounds__(512) gat_main(const float* __restrict__ glh,
                                                const float* __restrict__ grh,
                                                const int* __restrict__ adj,
                                                const float* __restrict__ attn_w,
                                                float* __restrict__ out) {
    const int hh  = blockIdx.y;
    const int i0  = blockIdx.x * 8;
    const int tid = threadIdx.x;

    __shared__ float p_buf[8][1028];
    __shared__ float part[8][16][32];
    __shared__ float red[8][8];
    __shared__ float l_sh[8];

    float lpart[8];
#pragma unroll
    for (int ii = 0; ii < 8; ++ii) lpart[ii] = 0.f;

    // ---- Phase A (e + exp + row-sum fused) ----
    for (int c = 0; c < 2; ++c) {
        const int j = (c << 9) + tid;
        const float* __restrict__ gp = glh + (hh * NN + j) * NHF;
        float gl[NHF];
#pragma unroll
        for (int f4 = 0; f4 < 8; ++f4) {
            const float4 v = *(const float4*)(gp + (f4 << 2));
            gl[4 * f4 + 0] = v.x; gl[4 * f4 + 1] = v.y;
            gl[4 * f4 + 2] = v.z; gl[4 * f4 + 3] = v.w;
        }
        float alpha = 0.f;
#pragma unroll
        for (int f = 0; f < NHF; ++f) alpha = fmaf(gl[f], attn_w[f], alpha);
        int adjv[8];
#pragma unroll
        for (int ii = 0; ii < 8; ++ii) adjv[ii] = adj[(i0 + ii) * NN + j];
#pragma unroll
        for (int ii = 0; ii < 8; ++ii) {
            const float* __restrict__ grp = grh + (hh * NN + i0 + ii) * NHF;  // uniform -> s_load
            float S0 = 0.f, S1 = 0.f;
#pragma unroll
            for (int f = 0; f < NHF; f += 2) {
                const float s0 = gl[f]     + grp[f];
                const float s1 = gl[f + 1] + grp[f + 1];
                S0 = fmaf(fabsf(s0), attn_w[f],     S0);
                S1 = fmaf(fabsf(s1), attn_w[f + 1], S1);
            }
            const float e = fmaf(0.4f, S0 + S1, 0.6f * alpha);
            const float p = adjv[ii] ? __expf(e) : 0.f;
            p_buf[ii][j] = p;
            lpart[ii] += p;
        }
    }

    // ---- row-sum reduction ----
    const int lane = tid & 63, wv = tid >> 6;
#pragma unroll
    for (int ii = 0; ii < 8; ++ii) {
        float v = lpart[ii];
#pragma unroll
        for (int d = 32; d > 0; d >>= 1) v += __shfl_xor(v, d);
        if (lane == 0) red[ii][wv] = v;
    }
    __syncthreads();
    if (tid < 8) {
        float l = red[tid][0];
#pragma unroll
        for (int w = 1; w < 8; ++w) l += red[tid][w];
        l_sh[tid] = l;
    }
    __syncthreads();

    // ---- Phase C ----
    const int f  = tid & 31;
    const int js = tid >> 5;
    const float* __restrict__ gp = grh + hh * NN * NHF + f;
    float o[8];
#pragma unroll
    for (int ii = 0; ii < 8; ++ii) o[ii] = 0.f;
    const int jb = js << 6;
    for (int jj = 0; jj < 64; jj += 4) {
        const int j = jb + jj;
        const float g0 = gp[(j + 0) * NHF];
        const float g1 = gp[(j + 1) * NHF];
        const float g2 = gp[(j + 2) * NHF];
        const float g3 = gp[(j + 3) * NHF];
#pragma unroll
        for (int ii = 0; ii < 8; ++ii) {
            const float4 p4 = *(const float4*)&p_buf[ii][j];
            o[ii] = fmaf(p4.x, g0, fmaf(p4.y, g1, fmaf(p4.z, g2, fmaf(p4.w, g3, o[ii]))));
        }
    }
#pragma unroll
    for (int ii = 0; ii < 8; ++ii) part[ii][js][f] = o[ii];
    __syncthreads();

    if (tid < 256) {
        const int ii = tid >> 5, ff = tid & 31;
        float s = 0.f;
#pragma unroll
        for (int k = 0; k < 16; ++k) s += part[ii][k][ff];
        s /= l_sh[ii];
        const float r = (s > 0.f) ? s : (__expf(s) - 1.f);
        out[(i0 + ii) * OUT_F + hh * NHF + ff] = r;
    }
}

extern "C" void kernel_launch(void* const* d_in, const int* in_sizes, int n_in,
                              void* d_out, int out_size, void* d_ws, size_t ws_size,
                              hipStream_t stream) {
    const float* hmat = (const float*)d_in[0];
    const int*   adj  = (const int*)d_in[1];
    const float* Wl   = (const float*)d_in[2];
    const float* Wr   = (const float*)d_in[3];
    const float* aw   = (const float*)d_in[4];
    float* o          = (float*)d_out;

    float* glh = (float*)d_ws;                 // [4][1024][32]
    float* grh = glh + NHEADS * NN * NHF;      // [4][1024][32]

    glr_gemm<<<dim3(256, 2), dim3(256), 0, stream>>>(hmat, Wl, Wr, glh, grh);
    gat_main<<<dim3(NN / 8, NHEADS), dim3(512), 0, stream>>>(glh, grh, adj, aw, o);
}